// Round 2
// baseline (567.310 us; speedup 1.0000x reference)
//
#include <hip/hip_runtime.h>
#include <hip/hip_bf16.h>

// GlobalSLC: out = out_s + out_d
//   static : y1 = ws@x; y2 = 2ws@y1 - x; y3 = 2ws@y2 - y1
//            pass1 reads ws fp32 ONCE and emits wsb = bf16(ws); passes 2,3 read wsb
//            (128 MiB, Infinity-Cache-resident) -> HBM traffic 768 MB -> ~390 MB.
//   dynamic: wd = x wp x^T never materialized; collapses to 32x32 algebra:
//            G = x^T x, W = G wp, H1 = W G, H2 = 2 W H1 - G
//   out = x@(2ts0 - td2) + xp@(G td1 + 2 H1 td2 + (2H2-G) td3) + y1@ts1 + y2@ts2 + y3@ts3

typedef __attribute__((ext_vector_type(8))) short short8;
typedef __attribute__((ext_vector_type(4))) float floatx4;

__device__ inline unsigned short f2bf(float f) {
    union { float f; unsigned u; } v; v.f = f;
    unsigned r = v.u + 0x7FFFu + ((v.u >> 16) & 1u);   // RNE
    return (unsigned short)(r >> 16);
}

// ---------- prep: xp = x@wp, Gram partials, Vt = bf16(x^T) ----------
__global__ __launch_bounds__(256) void k_prep(const float* __restrict__ x,
                                              const float* __restrict__ wp,
                                              float* __restrict__ xp,
                                              float* __restrict__ Gpart,
                                              unsigned short* __restrict__ Vt) {
    __shared__ float sx[8192];                 // 256 rows x 32 fp32 (32 KB)
    __shared__ float swp[1024];
    __shared__ unsigned short st[32][264];     // bf16 transpose staging
    const int t = threadIdx.x;
    const int n0 = blockIdx.x * 256;
    const floatx4* x4 = (const floatx4*)(x + (size_t)n0 * 32);
    floatx4* sx4 = (floatx4*)sx;
#pragma unroll
    for (int i = 0; i < 8; ++i) sx4[i * 256 + t] = x4[i * 256 + t];
    for (int i = t; i < 1024; i += 256) swp[i] = wp[i];
    __syncthreads();

    float row[32];
#pragma unroll
    for (int a = 0; a < 32; ++a) row[a] = sx[t * 32 + a];

    // xp row + bf16 transpose staging
    float* xpr = xp + (size_t)(n0 + t) * 32;
#pragma unroll
    for (int c = 0; c < 32; ++c) {
        float s = 0.f;
#pragma unroll
        for (int a = 0; a < 32; ++a) s += row[a] * swp[a * 32 + c];
        xpr[c] = s;
        st[c][t] = f2bf(row[c]);
    }

    // Gram partial: thread handles pairs (a = t>>3, b = 4*(t&7) .. +3)
    const int a = t >> 3;
    const int b = 4 * (t & 7);
    float g0 = 0.f, g1 = 0.f, g2 = 0.f, g3 = 0.f;
    for (int i = 0; i < 256; ++i) {
        float va = sx[i * 32 + a];
        floatx4 vb = *(floatx4*)&sx[i * 32 + b];
        g0 += va * vb.x; g1 += va * vb.y; g2 += va * vb.z; g3 += va * vb.w;
    }
    floatx4 g = {g0, g1, g2, g3};
    *(floatx4*)&Gpart[(size_t)blockIdx.x * 1024 + (size_t)(a * 32 + b)] = g;

    __syncthreads();
#pragma unroll
    for (int c = 0; c < 32; ++c) Vt[(size_t)c * 8192 + n0 + t] = st[c][t];
}

// ---------- 32x32 coefficient algebra (single block, 1024 threads) ----------
__global__ void k_coef(const float* __restrict__ Gpart, const float* __restrict__ wp,
                       const float* __restrict__ ts, const float* __restrict__ td,
                       float* __restrict__ Cx, float* __restrict__ Cxp) {
    __shared__ float G[1024], W[1024], H1[1024], H2[1024];
    __shared__ float swp[1024], td1[1024], td2[1024], td3[1024], ts0[1024];
    int t = threadIdx.x;
    int a = t >> 5, b = t & 31;
    float gs = 0.f;
    for (int p = 0; p < 32; ++p) gs += Gpart[p * 1024 + t];
    G[t] = gs; swp[t] = wp[t]; ts0[t] = ts[t];
    td1[t] = td[1024 + t]; td2[t] = td[2048 + t]; td3[t] = td[3072 + t];
    __syncthreads();
    float s = 0.f;
    for (int c = 0; c < 32; ++c) s += G[a * 32 + c] * swp[c * 32 + b];
    W[t] = s; __syncthreads();
    s = 0.f;
    for (int c = 0; c < 32; ++c) s += W[a * 32 + c] * G[c * 32 + b];
    H1[t] = s; __syncthreads();
    s = 0.f;
    for (int c = 0; c < 32; ++c) s += W[a * 32 + c] * H1[c * 32 + b];
    H2[t] = 2.f * s - G[t]; __syncthreads();
    s = 0.f;
    for (int c = 0; c < 32; ++c)
        s += G[a * 32 + c] * td1[c * 32 + b]
           + 2.f * H1[a * 32 + c] * td2[c * 32 + b]
           + (2.f * H2[a * 32 + c] - G[a * 32 + c]) * td3[c * 32 + b];
    Cxp[t] = s;
    Cx[t] = 2.f * ts0[t] - td2[t];
}

// ---------- big GEMM: Ypart[ksplit] = A(8192x8192) @ V(8192x32) partials ----------
// grid (128, 8): 64-row tiles x split-K(1024). 256 thr = 4 waves, wave per 16 rows.
// CONV: A fp32, staged via global_load_lds(16B) + XOR chunk swizzle, cvt bf16 in-reg,
//       AND stores the bf16 tile to wsb (one-time fp32->bf16 conversion, fused).
// !CONV: A already bf16 (wsb, L3-resident), 8 KB tiles, fragments = direct b128 reads.
template <bool CONV>
__global__ __launch_bounds__(256) void k_gemm(const float* __restrict__ Af,
                                              const unsigned short* __restrict__ Ab,
                                              unsigned short* __restrict__ wsb_out,
                                              const unsigned short* __restrict__ Vt,
                                              float* __restrict__ Ypart) {
    const int t = threadIdx.x;
    const int lane = t & 63;
    const int wv = t >> 6;
    const int l15 = lane & 15;
    const int l4 = lane >> 4;
    const int m0 = blockIdx.x * 64;
    const int k0 = blockIdx.y * 1024;

    floatx4 acc0 = {0.f, 0.f, 0.f, 0.f};
    floatx4 acc1 = {0.f, 0.f, 0.f, 0.f};

    if (CONV) {
        __shared__ float sm[64 * 64];          // 16 KB fp32 tile, 16B-chunk XOR swizzle
        for (int kt = 0; kt < 1024; kt += 64) {
            __syncthreads();
#pragma unroll
            for (int i = 0; i < 4; ++i) {
                int r = i * 16 + (t >> 4);
                int j = t & 15;
                int cch = j ^ (r & 15);
                const float* gsrc = Af + (size_t)(m0 + r) * 8192 + (k0 + kt) + cch * 4;
                float* ldst = &sm[(i * 16 + wv * 4) * 64];
                __builtin_amdgcn_global_load_lds(
                    (const __attribute__((address_space(1))) unsigned int*)gsrc,
                    (__attribute__((address_space(3))) unsigned int*)ldst, 16, 0, 0);
            }
            __syncthreads();
#pragma unroll
            for (int kh = 0; kh < 2; ++kh) {
                int rl = wv * 16 + l15;
                int jb = kh * 8 + l4 * 2;
                floatx4 f0 = *(floatx4*)&sm[rl * 64 + ((jb    ) ^ l15) * 4];
                floatx4 f1 = *(floatx4*)&sm[rl * 64 + ((jb + 1) ^ l15) * 4];
                short8 av;
                av[0] = f2bf(f0.x); av[1] = f2bf(f0.y); av[2] = f2bf(f0.z); av[3] = f2bf(f0.w);
                av[4] = f2bf(f1.x); av[5] = f2bf(f1.y); av[6] = f2bf(f1.z); av[7] = f2bf(f1.w);
                int kk = k0 + kt + kh * 32 + l4 * 8;
                *(short8*)(wsb_out + (size_t)(m0 + rl) * 8192 + kk) = av;   // fused conversion
                short8 b0 = *(const short8*)(Vt + (size_t)l15 * 8192 + kk);
                short8 b1 = *(const short8*)(Vt + (size_t)(16 + l15) * 8192 + kk);
                acc0 = __builtin_amdgcn_mfma_f32_16x16x32_bf16(av, b0, acc0, 0, 0, 0);
                acc1 = __builtin_amdgcn_mfma_f32_16x16x32_bf16(av, b1, acc1, 0, 0, 0);
            }
        }
    } else {
        __shared__ unsigned short sm16[64 * 64];   // 8 KB bf16 tile, XOR swizzle on 16B chunks
        for (int kt = 0; kt < 1024; kt += 64) {
            __syncthreads();
#pragma unroll
            for (int i = 0; i < 2; ++i) {
                int r = i * 32 + (t >> 3);
                int j = t & 7;
                int cch = j ^ (r & 7);
                const unsigned short* gsrc =
                    Ab + (size_t)(m0 + r) * 8192 + (k0 + kt) + cch * 8;
                unsigned short* ldst = &sm16[(i * 32 + wv * 8) * 64];
                __builtin_amdgcn_global_load_lds(
                    (const __attribute__((address_space(1))) unsigned int*)gsrc,
                    (__attribute__((address_space(3))) unsigned int*)ldst, 16, 0, 0);
            }
            __syncthreads();
#pragma unroll
            for (int kh = 0; kh < 2; ++kh) {
                int rl = wv * 16 + l15;
                short8 av = *(short8*)&sm16[rl * 64 + ((kh * 4 + l4) ^ (rl & 7)) * 8];
                int kk = k0 + kt + kh * 32 + l4 * 8;
                short8 b0 = *(const short8*)(Vt + (size_t)l15 * 8192 + kk);
                short8 b1 = *(const short8*)(Vt + (size_t)(16 + l15) * 8192 + kk);
                acc0 = __builtin_amdgcn_mfma_f32_16x16x32_bf16(av, b0, acc0, 0, 0, 0);
                acc1 = __builtin_amdgcn_mfma_f32_16x16x32_bf16(av, b1, acc1, 0, 0, 0);
            }
        }
    }
    // C/D layout: col = lane&15, row = (lane>>4)*4 + i ; private per-ksplit partials
    float* yp = Ypart + (size_t)blockIdx.y * 262144;
    int row0 = m0 + wv * 16 + l4 * 4;
#pragma unroll
    for (int i = 0; i < 4; ++i) {
        yp[(size_t)(row0 + i) * 32 + l15] = acc0[i];
        yp[(size_t)(row0 + i) * 32 + 16 + l15] = acc1[i];
    }
}

// ---------- reduce split-K partials + alpha/beta + emit y and bf16(y^T) ----------
// y = alpha * sum_p Ypart[p] + beta * prev ; Vt = bf16(y^T)
__global__ __launch_bounds__(256) void k_trans(const float* __restrict__ Ypart,
                                               const float* __restrict__ prev,
                                               float alpha, float beta,
                                               float* __restrict__ y,
                                               unsigned short* __restrict__ Vt) {
    __shared__ unsigned short st[32][264];
    const int t = threadIdx.x;
    const int n0 = blockIdx.x * 256;
    const size_t base4 = (size_t)n0 * 8;       // float4 index of row n0
    floatx4 r[8];
#pragma unroll
    for (int j = 0; j < 8; ++j) r[j] = {0.f, 0.f, 0.f, 0.f};
    for (int p = 0; p < 8; ++p) {
        const floatx4* P4 = (const floatx4*)(Ypart + (size_t)p * 262144);
#pragma unroll
        for (int j = 0; j < 8; ++j) r[j] += P4[base4 + j * 256 + t];
    }
    const floatx4* prev4 = (const floatx4*)prev;
    floatx4* y4 = (floatx4*)y;
#pragma unroll
    for (int j = 0; j < 8; ++j) {
        floatx4 pv = prev4[base4 + j * 256 + t];
        floatx4 v;
        v.x = alpha * r[j].x + beta * pv.x;
        v.y = alpha * r[j].y + beta * pv.y;
        v.z = alpha * r[j].z + beta * pv.z;
        v.w = alpha * r[j].w + beta * pv.w;
        y4[base4 + j * 256 + t] = v;
        int q = j * 256 + t;
        int lr = q >> 3;                       // local row 0..255
        int c4 = (q & 7) * 4;                  // starting col
        st[c4 + 0][lr] = f2bf(v.x);
        st[c4 + 1][lr] = f2bf(v.y);
        st[c4 + 2][lr] = f2bf(v.z);
        st[c4 + 3][lr] = f2bf(v.w);
    }
    __syncthreads();
#pragma unroll
    for (int c = 0; c < 32; ++c) Vt[(size_t)c * 8192 + n0 + t] = st[c][t];
}

// ---------- out = x@Cx + xp@Cxp + y1@ts1 + y2@ts2 + y3@ts3 ----------
__global__ void k_final(const float* __restrict__ x, const float* __restrict__ xp,
                        const float* __restrict__ y1, const float* __restrict__ y2,
                        const float* __restrict__ y3, const float* __restrict__ Cx,
                        const float* __restrict__ Cxp, const float* __restrict__ ts,
                        float* __restrict__ out) {
    __shared__ float m0[1024], m1[1024], m2[1024], m3[1024], m4[1024];
    int t = threadIdx.x;
    for (int i = t; i < 1024; i += 256) {
        m0[i] = Cx[i]; m1[i] = Cxp[i];
        m2[i] = ts[1024 + i]; m3[i] = ts[2048 + i]; m4[i] = ts[3072 + i];
    }
    __syncthreads();
    int g = blockIdx.x * 256 + t;
    int n = g >> 5, c = g & 31;
    const float* xr  = x  + (size_t)n * 32;
    const float* xpr = xp + (size_t)n * 32;
    const float* y1r = y1 + (size_t)n * 32;
    const float* y2r = y2 + (size_t)n * 32;
    const float* y3r = y3 + (size_t)n * 32;
    float s = 0.f;
#pragma unroll
    for (int a = 0; a < 32; ++a) {
        s += xr[a]  * m0[a * 32 + c]
           + xpr[a] * m1[a * 32 + c]
           + y1r[a] * m2[a * 32 + c]
           + y2r[a] * m3[a * 32 + c]
           + y3r[a] * m4[a * 32 + c];
    }
    out[g] = s;
}

extern "C" void kernel_launch(void* const* d_in, const int* in_sizes, int n_in,
                              void* d_out, int out_size, void* d_ws, size_t ws_size,
                              hipStream_t stream) {
    const float* x  = (const float*)d_in[0];   // 8192 x 32
    const float* ws = (const float*)d_in[1];   // 8192 x 8192
    const float* wp = (const float*)d_in[2];   // 32 x 32
    const float* ts = (const float*)d_in[3];   // 4 x 32 x 32
    const float* td = (const float*)d_in[4];   // 4 x 32 x 32
    float* out = (float*)d_out;

    char* w = (char*)d_ws;
    unsigned short* wsb = (unsigned short*)w;                  // 8192x8192 bf16 (128 MB)
    float* Ppart = (float*)(w + 134217728);                    // 8 x 8192 x 32 fp32 (8 MB)
    float* xp  = Ppart + 2097152;                              // 1 MB each
    float* y1  = xp + 262144;
    float* y2  = y1 + 262144;
    float* y3  = y2 + 262144;
    unsigned short* Vt = (unsigned short*)(y3 + 262144);       // 32 x 8192 bf16 (512 KB)
    float* Gpart = (float*)(Vt + 262144);                      // 32 x 1024 (128 KB)
    float* Cx  = Gpart + 32768;
    float* Cxp = Cx + 1024;

    dim3 gg(128, 8);
    k_prep<<<32, 256, 0, stream>>>(x, wp, xp, Gpart, Vt);
    k_coef<<<1, 1024, 0, stream>>>(Gpart, wp, ts, td, Cx, Cxp);
    // pass 1: y1 = ws @ x   (+ fused ws -> bf16 conversion)
    k_gemm<true><<<gg, 256, 0, stream>>>(ws, nullptr, wsb, Vt, Ppart);
    k_trans<<<32, 256, 0, stream>>>(Ppart, x, 1.0f, 0.0f, y1, Vt);
    // pass 2: y2 = 2 ws @ y1 - x
    k_gemm<false><<<gg, 256, 0, stream>>>(nullptr, wsb, nullptr, Vt, Ppart);
    k_trans<<<32, 256, 0, stream>>>(Ppart, x, 2.0f, -1.0f, y2, Vt);
    // pass 3: y3 = 2 ws @ y2 - y1
    k_gemm<false><<<gg, 256, 0, stream>>>(nullptr, wsb, nullptr, Vt, Ppart);
    k_trans<<<32, 256, 0, stream>>>(Ppart, y1, 2.0f, -1.0f, y3, Vt);

    k_final<<<1024, 256, 0, stream>>>(x, xp, y1, y2, y3, Cx, Cxp, ts, out);
}

// Round 3
// 541.584 us; speedup vs baseline: 1.0475x; 1.0475x over previous
//
#include <hip/hip_runtime.h>
#include <hip/hip_bf16.h>

// GlobalSLC: out = out_s + out_d
//   static : y1 = ws@x; y2 = 2ws@y1 - x; y3 = 2ws@y2 - y1
//   dynamic: collapses to 32x32 algebra (G = x^T x, W = G wp, H1 = W G, H2 = 2 W H1 - G)
//   out = x@(2ts0-td2) + xp@(G td1 + 2 H1 td2 + (2H2-G) td3) + y1@ts1 + y2@ts2 + y3@ts3
//
// R3 gemm design: NO LDS, NO barriers. wsb (bf16 ws) is stored FRAGMENT-ORDERED so each
// lane's 16-B MFMA A-fragment is a contiguous, lane-consecutive global load. K-loop =
// load->mfma only; loads pipeline freely under vmcnt (no barrier drain, the R2 killer).

typedef __attribute__((ext_vector_type(8))) short short8;
typedef __attribute__((ext_vector_type(4))) float floatx4;

constexpr int NSPLIT = 16;      // split-K factor; 512 cols per split
constexpr int KT_PER = 8;       // 64-col k-tiles per split

__device__ inline unsigned short f2bf(float f) {
    union { float f; unsigned u; } v; v.f = f;
    unsigned r = v.u + 0x7FFFu + ((v.u >> 16) & 1u);   // RNE
    return (unsigned short)(r >> 16);
}

// ---------- prep: xp = x@wp, Gram partials, Vt = bf16(x^T) ----------
__global__ __launch_bounds__(256) void k_prep(const float* __restrict__ x,
                                              const float* __restrict__ wp,
                                              float* __restrict__ xp,
                                              float* __restrict__ Gpart,
                                              unsigned short* __restrict__ Vt) {
    __shared__ float sx[8192];
    __shared__ float swp[1024];
    __shared__ unsigned short st[32][264];
    const int t = threadIdx.x;
    const int n0 = blockIdx.x * 256;
    const floatx4* x4 = (const floatx4*)(x + (size_t)n0 * 32);
    floatx4* sx4 = (floatx4*)sx;
#pragma unroll
    for (int i = 0; i < 8; ++i) sx4[i * 256 + t] = x4[i * 256 + t];
    for (int i = t; i < 1024; i += 256) swp[i] = wp[i];
    __syncthreads();

    float row[32];
#pragma unroll
    for (int a = 0; a < 32; ++a) row[a] = sx[t * 32 + a];

    float* xpr = xp + (size_t)(n0 + t) * 32;
#pragma unroll
    for (int c = 0; c < 32; ++c) {
        float s = 0.f;
#pragma unroll
        for (int a = 0; a < 32; ++a) s += row[a] * swp[a * 32 + c];
        xpr[c] = s;
        st[c][t] = f2bf(row[c]);
    }

    const int a = t >> 3;
    const int b = 4 * (t & 7);
    float g0 = 0.f, g1 = 0.f, g2 = 0.f, g3 = 0.f;
    for (int i = 0; i < 256; ++i) {
        float va = sx[i * 32 + a];
        floatx4 vb = *(floatx4*)&sx[i * 32 + b];
        g0 += va * vb.x; g1 += va * vb.y; g2 += va * vb.z; g3 += va * vb.w;
    }
    floatx4 g = {g0, g1, g2, g3};
    *(floatx4*)&Gpart[(size_t)blockIdx.x * 1024 + (size_t)(a * 32 + b)] = g;

    __syncthreads();
#pragma unroll
    for (int c = 0; c < 32; ++c) Vt[(size_t)c * 8192 + n0 + t] = st[c][t];
}

// ---------- 32x32 coefficient algebra ----------
__global__ void k_coef(const float* __restrict__ Gpart, const float* __restrict__ wp,
                       const float* __restrict__ ts, const float* __restrict__ td,
                       float* __restrict__ Cx, float* __restrict__ Cxp) {
    __shared__ float G[1024], W[1024], H1[1024], H2[1024];
    __shared__ float swp[1024], td1[1024], td2[1024], td3[1024], ts0[1024];
    int t = threadIdx.x;
    int a = t >> 5, b = t & 31;
    float gs = 0.f;
    for (int p = 0; p < 32; ++p) gs += Gpart[p * 1024 + t];
    G[t] = gs; swp[t] = wp[t]; ts0[t] = ts[t];
    td1[t] = td[1024 + t]; td2[t] = td[2048 + t]; td3[t] = td[3072 + t];
    __syncthreads();
    float s = 0.f;
    for (int c = 0; c < 32; ++c) s += G[a * 32 + c] * swp[c * 32 + b];
    W[t] = s; __syncthreads();
    s = 0.f;
    for (int c = 0; c < 32; ++c) s += W[a * 32 + c] * G[c * 32 + b];
    H1[t] = s; __syncthreads();
    s = 0.f;
    for (int c = 0; c < 32; ++c) s += W[a * 32 + c] * H1[c * 32 + b];
    H2[t] = 2.f * s - G[t]; __syncthreads();
    s = 0.f;
    for (int c = 0; c < 32; ++c)
        s += G[a * 32 + c] * td1[c * 32 + b]
           + 2.f * H1[a * 32 + c] * td2[c * 32 + b]
           + (2.f * H2[a * 32 + c] - G[a * 32 + c]) * td3[c * 32 + b];
    Cxp[t] = s;
    Cx[t] = 2.f * ts0[t] - td2[t];
}

// ---------- pass 1: Ypart = ws(fp32) @ V partials, fused fragment-ordered bf16 emit ----------
// grid (128, NSPLIT) x 256. Wave wv owns rows bx*64+wv*16..+15, cols by*512..+511.
// Per (kt,i): lane reads 32 B fp32 (wave = 16 rows x 128 B full lines, advancing
// sequentially), cvt->bf16, store 16 B fragment (wave store = 1 KB contiguous), 2 MFMAs.
__global__ __launch_bounds__(256) void k_gemm1(const float* __restrict__ A,
                                               unsigned short* __restrict__ wsb,
                                               const unsigned short* __restrict__ Vt,
                                               float* __restrict__ Ypart) {
    const int t = threadIdx.x;
    const int lane = t & 63;
    const int wv = t >> 6;
    const int l15 = lane & 15;
    const int l4 = lane >> 4;
    const int bx = blockIdx.x, by = blockIdx.y;
    const int k0 = by * 512;
    const int row = bx * 64 + wv * 16 + l15;

    const float* arow = A + (size_t)row * 8192 + k0 + l4 * 8;
    unsigned short* wout =
        wsb + (((size_t)(bx * NSPLIT + by) * 4096) + (size_t)wv * 64 + lane) * 8;
    const unsigned short* vb0 = Vt + (size_t)l15 * 8192 + k0 + l4 * 8;
    const unsigned short* vb1 = vb0 + (size_t)16 * 8192;

    floatx4 acc0 = {0.f, 0.f, 0.f, 0.f};
    floatx4 acc1 = {0.f, 0.f, 0.f, 0.f};

#pragma unroll
    for (int kt = 0; kt < KT_PER; ++kt) {
#pragma unroll
        for (int i = 0; i < 2; ++i) {
            const int kk = kt * 64 + i * 32;
            floatx4 f0 = *(const floatx4*)(arow + kk);
            floatx4 f1 = *(const floatx4*)(arow + kk + 4);
            short8 av;
            av[0] = f2bf(f0.x); av[1] = f2bf(f0.y); av[2] = f2bf(f0.z); av[3] = f2bf(f0.w);
            av[4] = f2bf(f1.x); av[5] = f2bf(f1.y); av[6] = f2bf(f1.z); av[7] = f2bf(f1.w);
            *(short8*)(wout + (size_t)(kt * 2 + i) * 2048) = av;
            short8 b0 = *(const short8*)(vb0 + kk);
            short8 b1 = *(const short8*)(vb1 + kk);
            acc0 = __builtin_amdgcn_mfma_f32_16x16x32_bf16(av, b0, acc0, 0, 0, 0);
            acc1 = __builtin_amdgcn_mfma_f32_16x16x32_bf16(av, b1, acc1, 0, 0, 0);
        }
    }
    float* yp = Ypart + (size_t)by * 262144;
    const int row0 = bx * 64 + wv * 16 + l4 * 4;
#pragma unroll
    for (int r = 0; r < 4; ++r) {
        yp[(size_t)(row0 + r) * 32 + l15] = acc0[r];
        yp[(size_t)(row0 + r) * 32 + 16 + l15] = acc1[r];
    }
}

// ---------- passes 2,3: Ypart = wsb(bf16, fragment-ordered) @ V partials ----------
__global__ __launch_bounds__(256) void k_gemm2(const unsigned short* __restrict__ wsb,
                                               const unsigned short* __restrict__ Vt,
                                               float* __restrict__ Ypart) {
    const int t = threadIdx.x;
    const int lane = t & 63;
    const int wv = t >> 6;
    const int l15 = lane & 15;
    const int l4 = lane >> 4;
    const int bx = blockIdx.x, by = blockIdx.y;
    const int k0 = by * 512;

    const short8* win = (const short8*)wsb
        + ((size_t)(bx * NSPLIT + by) * 4096) + (size_t)wv * 64 + lane;
    const unsigned short* vb0 = Vt + (size_t)l15 * 8192 + k0 + l4 * 8;
    const unsigned short* vb1 = vb0 + (size_t)16 * 8192;

    floatx4 acc0 = {0.f, 0.f, 0.f, 0.f};
    floatx4 acc1 = {0.f, 0.f, 0.f, 0.f};

#pragma unroll
    for (int kt = 0; kt < KT_PER; ++kt) {
#pragma unroll
        for (int i = 0; i < 2; ++i) {
            const int kk = kt * 64 + i * 32;
            short8 av = win[(size_t)(kt * 2 + i) * 256];
            short8 b0 = *(const short8*)(vb0 + kk);
            short8 b1 = *(const short8*)(vb1 + kk);
            acc0 = __builtin_amdgcn_mfma_f32_16x16x32_bf16(av, b0, acc0, 0, 0, 0);
            acc1 = __builtin_amdgcn_mfma_f32_16x16x32_bf16(av, b1, acc1, 0, 0, 0);
        }
    }
    float* yp = Ypart + (size_t)by * 262144;
    const int row0 = bx * 64 + wv * 16 + l4 * 4;
#pragma unroll
    for (int r = 0; r < 4; ++r) {
        yp[(size_t)(row0 + r) * 32 + l15] = acc0[r];
        yp[(size_t)(row0 + r) * 32 + 16 + l15] = acc1[r];
    }
}

// ---------- reduce split-K partials + alpha/beta + emit y and bf16(y^T) ----------
__global__ __launch_bounds__(256) void k_trans(const float* __restrict__ Ypart,
                                               const float* __restrict__ prev,
                                               float alpha, float beta,
                                               float* __restrict__ y,
                                               unsigned short* __restrict__ Vt) {
    __shared__ unsigned short st[32][264];
    const int t = threadIdx.x;
    const int n0 = blockIdx.x * 256;
    const size_t base4 = (size_t)n0 * 8;
    floatx4 r[8];
#pragma unroll
    for (int j = 0; j < 8; ++j) r[j] = {0.f, 0.f, 0.f, 0.f};
    for (int p = 0; p < NSPLIT; ++p) {
        const floatx4* P4 = (const floatx4*)(Ypart + (size_t)p * 262144);
#pragma unroll
        for (int j = 0; j < 8; ++j) r[j] += P4[base4 + j * 256 + t];
    }
    const floatx4* prev4 = (const floatx4*)prev;
    floatx4* y4 = (floatx4*)y;
#pragma unroll
    for (int j = 0; j < 8; ++j) {
        floatx4 pv = prev4[base4 + j * 256 + t];
        floatx4 v;
        v.x = alpha * r[j].x + beta * pv.x;
        v.y = alpha * r[j].y + beta * pv.y;
        v.z = alpha * r[j].z + beta * pv.z;
        v.w = alpha * r[j].w + beta * pv.w;
        y4[base4 + j * 256 + t] = v;
        int q = j * 256 + t;
        int lr = q >> 3;
        int c4 = (q & 7) * 4;
        st[c4 + 0][lr] = f2bf(v.x);
        st[c4 + 1][lr] = f2bf(v.y);
        st[c4 + 2][lr] = f2bf(v.z);
        st[c4 + 3][lr] = f2bf(v.w);
    }
    __syncthreads();
#pragma unroll
    for (int c = 0; c < 32; ++c) Vt[(size_t)c * 8192 + n0 + t] = st[c][t];
}

// ---------- out = x@Cx + xp@Cxp + y1@ts1 + y2@ts2 + y3@ts3 ----------
__global__ void k_final(const float* __restrict__ x, const float* __restrict__ xp,
                        const float* __restrict__ y1, const float* __restrict__ y2,
                        const float* __restrict__ y3, const float* __restrict__ Cx,
                        const float* __restrict__ Cxp, const float* __restrict__ ts,
                        float* __restrict__ out) {
    __shared__ float m0[1024], m1[1024], m2[1024], m3[1024], m4[1024];
    int t = threadIdx.x;
    for (int i = t; i < 1024; i += 256) {
        m0[i] = Cx[i]; m1[i] = Cxp[i];
        m2[i] = ts[1024 + i]; m3[i] = ts[2048 + i]; m4[i] = ts[3072 + i];
    }
    __syncthreads();
    int g = blockIdx.x * 256 + t;
    int n = g >> 5, c = g & 31;
    const float* xr  = x  + (size_t)n * 32;
    const float* xpr = xp + (size_t)n * 32;
    const float* y1r = y1 + (size_t)n * 32;
    const float* y2r = y2 + (size_t)n * 32;
    const float* y3r = y3 + (size_t)n * 32;
    float s = 0.f;
#pragma unroll
    for (int a = 0; a < 32; ++a) {
        s += xr[a]  * m0[a * 32 + c]
           + xpr[a] * m1[a * 32 + c]
           + y1r[a] * m2[a * 32 + c]
           + y2r[a] * m3[a * 32 + c]
           + y3r[a] * m4[a * 32 + c];
    }
    out[g] = s;
}

extern "C" void kernel_launch(void* const* d_in, const int* in_sizes, int n_in,
                              void* d_out, int out_size, void* d_ws, size_t ws_size,
                              hipStream_t stream) {
    const float* x  = (const float*)d_in[0];   // 8192 x 32
    const float* ws = (const float*)d_in[1];   // 8192 x 8192
    const float* wp = (const float*)d_in[2];   // 32 x 32
    const float* ts = (const float*)d_in[3];   // 4 x 32 x 32
    const float* td = (const float*)d_in[4];   // 4 x 32 x 32
    float* out = (float*)d_out;

    char* w = (char*)d_ws;
    unsigned short* wsb = (unsigned short*)w;              // 128 MB, fragment-ordered bf16
    float* Ppart = (float*)(w + 134217728);                // NSPLIT x 8192 x 32 (16 MB)
    float* xp  = Ppart + (size_t)NSPLIT * 262144;
    float* y1  = xp + 262144;
    float* y2  = y1 + 262144;
    float* y3  = y2 + 262144;
    unsigned short* Vt = (unsigned short*)(y3 + 262144);   // 32 x 8192 bf16
    float* Gpart = (float*)(Vt + 262144);                  // 32 x 1024
    float* Cx  = Gpart + 32768;
    float* Cxp = Cx + 1024;

    dim3 gg(128, NSPLIT);
    k_prep<<<32, 256, 0, stream>>>(x, wp, xp, Gpart, Vt);
    k_coef<<<1, 1024, 0, stream>>>(Gpart, wp, ts, td, Cx, Cxp);
    // pass 1: y1 = ws @ x   (+ fused fragment-ordered bf16 emit)
    k_gemm1<<<gg, 256, 0, stream>>>(ws, wsb, Vt, Ppart);
    k_trans<<<32, 256, 0, stream>>>(Ppart, x, 1.0f, 0.0f, y1, Vt);
    // pass 2: y2 = 2 ws @ y1 - x
    k_gemm2<<<gg, 256, 0, stream>>>(wsb, Vt, Ppart);
    k_trans<<<32, 256, 0, stream>>>(Ppart, x, 2.0f, -1.0f, y2, Vt);
    // pass 3: y3 = 2 ws @ y2 - y1
    k_gemm2<<<gg, 256, 0, stream>>>(wsb, Vt, Ppart);
    k_trans<<<32, 256, 0, stream>>>(Ppart, y1, 2.0f, -1.0f, y3, Vt);

    k_final<<<1024, 256, 0, stream>>>(x, xp, y1, y2, y3, Cx, Cxp, ts, out);
}